// Round 2
// baseline (455.882 us; speedup 1.0000x reference)
//
#include <hip/hip_runtime.h>

#define B_ 64
#define S_ 512
#define H_ 1024
#define M_ (B_*S_)   // 32768

typedef unsigned int u32;
typedef unsigned short u16;
typedef __attribute__((ext_vector_type(8))) short bf16x8;
typedef __attribute__((ext_vector_type(4))) float f32x4;

__device__ __forceinline__ u16 f2bf(float f) {
  u32 u = __builtin_bit_cast(u32, f);
  u += 0x7fffu + ((u >> 16) & 1u);
  return (u16)(u >> 16);
}
__device__ __forceinline__ u32 pk2(float a, float b) {
  return (u32)f2bf(a) | ((u32)f2bf(b) << 16);
}
__device__ __forceinline__ float tanh_fast(float x) {
  x = fminf(fmaxf(x, -20.f), 20.f);
  float e = __expf(2.f * x);
  return (e - 1.f) / (e + 1.f);
}
__device__ __forceinline__ void gload_lds16(const u16* g, u16* l) {
  __builtin_amdgcn_global_load_lds(
      (const __attribute__((address_space(1))) u32*)g,
      (__attribute__((address_space(3))) u32*)l, 16, 0, 0);
}

// K0: W2bf[n][k] = bf16(W_h[n][1024+k]), contiguous [1024][1024]
__global__ void conv_w2(const float* __restrict__ Wh, u16* __restrict__ W2bf) {
  int idx = blockIdx.x * 256 + threadIdx.x;      // 262144 threads x 4 elems
  int n = idx >> 8;
  int k = (idx & 255) * 4;
  float4 x = *(const float4*)(Wh + (size_t)n * 2048 + 1024 + k);
  uint2 p; p.x = pk2(x.x, x.y); p.y = pk2(x.z, x.w);
  *(uint2*)(W2bf + (size_t)n * 1024 + k) = p;
}

// K1: part1[b][h] = sum_k dh[b][k] * W_h[h][k]  (k < 1024), f32
__global__ void part1_kernel(const float* __restrict__ dh,
                             const float* __restrict__ Wh,
                             float* __restrict__ part1) {
  __shared__ float dhs[1024];
  int t = threadIdx.x;               // 256
  int hc = blockIdx.x;               // 0..3
  int b  = blockIdx.y;               // 0..63
  ((float4*)dhs)[t] = ((const float4*)(dh + b * 1024))[t];
  __syncthreads();
  int h = hc * 256 + t;
  const float4* wr = (const float4*)(Wh + (size_t)h * 2048);
  const float4* dv = (const float4*)dhs;
  float acc = 0.f;
#pragma unroll 8
  for (int k4 = 0; k4 < 256; ++k4) {
    float4 w = wr[k4];
    float4 d = dv[k4];
    acc += w.x * d.x + w.y * d.y + w.z * d.z + w.w * d.w;
  }
  part1[b * 1024 + h] = acc;
}

// K3: fused GEMM (enc @ W2^T) + tanh + v-dot -> scores (global atomic accum)
__global__ __launch_bounds__(256) void gemm_scores(
    const float* __restrict__ enc, const u16* __restrict__ W2bf,
    const float* __restrict__ part1, const float* __restrict__ v,
    float* __restrict__ scores) {
  __shared__ __align__(16) u16 As[128 * 64];
  __shared__ __align__(16) u16 Bs[128 * 64];
  __shared__ float sc_lds[128];
  const int tid = threadIdx.x;
  const int lane = tid & 63, wid = tid >> 6;
  const int wr = wid >> 1, wc = wid & 1;
  const int l15 = lane & 15, lhi = lane >> 4;
  const int r0 = blockIdx.x * 128;     // rows: b*512+s
  const int n0 = blockIdx.y * 128;     // cols: h
  const int bb = r0 >> 9;

  f32x4 acc[4][4] = {};

  const int brow = wid * 8 + (lane >> 3);   // + c*32
  const int bk = (lane & 7) * 8;

  for (int k0 = 0; k0 < 1024; k0 += 64) {
    // B tile: async global->LDS, 16B/lane, linear [n][k] layout
#pragma unroll
    for (int c = 0; c < 4; ++c) {
      const u16* src = W2bf + (size_t)(n0 + c * 32 + brow) * 1024 + k0 + bk;
      gload_lds16(src, Bs + c * 2048 + wid * 512);
    }
    // A tile: f32 load -> bf16 cvt -> LDS (reg-staged)
#pragma unroll
    for (int i = 0; i < 4; ++i) {
      int f = 2 * tid + 512 * i;           // float4 index in 128x16 grid
      int arow = f >> 4, c4 = f & 15;
      const float4* src =
          (const float4*)(enc + (size_t)(r0 + arow) * 1024 + k0 + c4 * 4);
      float4 x = src[0], y = src[1];
      uint4 p;
      p.x = pk2(x.x, x.y); p.y = pk2(x.z, x.w);
      p.z = pk2(y.x, y.y); p.w = pk2(y.z, y.w);
      *(uint4*)&As[arow * 64 + c4 * 4] = p;
    }
    __syncthreads();
#pragma unroll
    for (int kk = 0; kk < 2; ++kk) {
      const int kofs = kk * 32 + lhi * 8;
      bf16x8 af[4], bfr[4];
#pragma unroll
      for (int i = 0; i < 4; ++i)
        af[i] = *(const bf16x8*)&As[(wr * 64 + i * 16 + l15) * 64 + kofs];
#pragma unroll
      for (int j = 0; j < 4; ++j)
        bfr[j] = *(const bf16x8*)&Bs[(wc * 64 + j * 16 + l15) * 64 + kofs];
#pragma unroll
      for (int i = 0; i < 4; ++i)
#pragma unroll
        for (int j = 0; j < 4; ++j)
          acc[i][j] = __builtin_amdgcn_mfma_f32_16x16x32_bf16(
              af[i], bfr[j], acc[i][j], 0, 0, 0);
    }
    __syncthreads();
  }

  // epilogue: e = tanh(acc + part1[b][col]); partial score += e * v[col]
  if (tid < 128) sc_lds[tid] = 0.f;
  __syncthreads();
  float ps[4][4] = {};
#pragma unroll
  for (int j = 0; j < 4; ++j) {
    int col = n0 + wc * 64 + j * 16 + l15;
    float pv = part1[bb * 1024 + col];
    float vv = v[col];
#pragma unroll
    for (int i = 0; i < 4; ++i)
#pragma unroll
      for (int q = 0; q < 4; ++q)
        ps[i][q] += tanh_fast(acc[i][j][q] + pv) * vv;
  }
#pragma unroll
  for (int i = 0; i < 4; ++i)
#pragma unroll
    for (int q = 0; q < 4; ++q)
      atomicAdd(&sc_lds[wr * 64 + i * 16 + lhi * 4 + q], ps[i][q]);
  __syncthreads();
  if (tid < 128) atomicAdd(&scores[r0 + tid], sc_lds[tid]);
}

// K4: softmax over batch dim (axis=0) per s-column, times mask[s][b]
__global__ void softmax_col(const float* __restrict__ scores,
                            const float* __restrict__ mask,
                            float* __restrict__ a_raw) {
  int s = blockIdx.x;       // 512
  int b = threadIdx.x;      // 64 = 1 wave
  float x = scores[b * 512 + s];
  float m = x;
  for (int o = 32; o; o >>= 1) m = fmaxf(m, __shfl_xor(m, o));
  float e = __expf(x - m);
  float sum = e;
  for (int o = 32; o; o >>= 1) sum += __shfl_xor(sum, o);
  a_raw[b * 512 + s] = (e / sum) * mask[s * 64 + b];
}

// K5: normalize each b-row over s, write final a
__global__ void norm_rows(const float* __restrict__ a_raw,
                          float* __restrict__ out_a) {
  __shared__ float wsum[4];
  int b = blockIdx.x, t = threadIdx.x;   // 256
  float va = a_raw[b * 512 + t];
  float vb = a_raw[b * 512 + 256 + t];
  float sum = va + vb;
  for (int o = 32; o; o >>= 1) sum += __shfl_xor(sum, o);
  if ((t & 63) == 0) wsum[t >> 6] = sum;
  __syncthreads();
  float tot = wsum[0] + wsum[1] + wsum[2] + wsum[3];
  float inv = 1.f / (tot + 1e-10f);
  out_a[b * 512 + t] = va * inv;
  out_a[b * 512 + 256 + t] = vb * inv;
}

// K6: context[b][h] = sum_s a[b][s] * enc[b][s][h]
__global__ void context_kernel(const float* __restrict__ a,
                               const float* __restrict__ enc,
                               float* __restrict__ ctx) {
  int b = blockIdx.x, hc = blockIdx.y, t = threadIdx.x;  // 128 thr
  int h = hc * 128 + t;
  const float* ep = enc + (size_t)b * 512 * 1024 + h;
  const float* ap = a + b * 512;
  float acc = 0.f;
#pragma unroll 8
  for (int s = 0; s < 512; ++s) acc += ap[s] * ep[(size_t)s * 1024];
  ctx[b * 1024 + h] = acc;
}

extern "C" void kernel_launch(void* const* d_in, const int* in_sizes, int n_in,
                              void* d_out, int out_size, void* d_ws,
                              size_t ws_size, hipStream_t stream) {
  const float* enc  = (const float*)d_in[0];
  const float* dh   = (const float*)d_in[1];
  const float* mask = (const float*)d_in[2];
  const float* Wh   = (const float*)d_in[3];
  const float* v    = (const float*)d_in[4];
  float* out_a   = (float*)d_out;         // [64,1,512]  = 32768
  float* out_ctx = out_a + M_;            // [64,1,1024] = 65536

  char* ws = (char*)d_ws;
  u16*   W2bf   = (u16*)ws;                                   // 2 MB
  float* part1  = (float*)(ws + (2u << 20));                  // 256 KB
  float* scores = (float*)(ws + (2u << 20) + (256u << 10));   // 128 KB
  float* a_raw  = (float*)(ws + (2u << 20) + (384u << 10));   // 128 KB

  hipMemsetAsync(scores, 0, M_ * sizeof(float), stream);
  conv_w2<<<1024, 256, 0, stream>>>(Wh, W2bf);
  part1_kernel<<<dim3(4, 64), 256, 0, stream>>>(dh, Wh, part1);
  gemm_scores<<<dim3(256, 8), 256, 0, stream>>>(enc, W2bf, part1, v, scores);
  softmax_col<<<512, 64, 0, stream>>>(scores, mask, a_raw);
  norm_rows<<<64, 256, 0, stream>>>(a_raw, out_a);
  context_kernel<<<dim3(64, 8), 128, 0, stream>>>(out_a, enc, out_ctx);
}

// Round 3
// 446.011 us; speedup vs baseline: 1.0221x; 1.0221x over previous
//
#include <hip/hip_runtime.h>

#define B_ 64
#define S_ 512
#define H_ 1024
#define M_ (B_*S_)   // 32768

typedef unsigned int u32;
typedef unsigned short u16;
typedef __attribute__((ext_vector_type(8))) short bf16x8;
typedef __attribute__((ext_vector_type(4))) float f32x4;

__device__ __forceinline__ u16 f2bf(float f) {
  u32 u = __builtin_bit_cast(u32, f);
  u += 0x7fffu + ((u >> 16) & 1u);
  return (u16)(u >> 16);
}
__device__ __forceinline__ u32 pk2(float a, float b) {
  return (u32)f2bf(a) | ((u32)f2bf(b) << 16);
}
__device__ __forceinline__ float tanh_fast(float x) {
  x = fminf(fmaxf(x, -20.f), 20.f);
  float e = __expf(2.f * x);
  return (e - 1.f) / (e + 1.f);
}
__device__ __forceinline__ void gload_lds16(const u16* g, u16* l) {
  __builtin_amdgcn_global_load_lds(
      (const __attribute__((address_space(1))) u32*)g,
      (__attribute__((address_space(3))) u32*)l, 16, 0, 0);
}

// K0: W2bf[n][k] = bf16(W_h[n][1024+k]), linear [1024][1024]
__global__ void conv_w2(const float* __restrict__ Wh, u16* __restrict__ W2bf) {
  int idx = blockIdx.x * 256 + threadIdx.x;
  int n = idx >> 8;
  int k = (idx & 255) * 4;
  float4 x = *(const float4*)(Wh + (size_t)n * 2048 + 1024 + k);
  uint2 p; p.x = pk2(x.x, x.y); p.y = pk2(x.z, x.w);
  *(uint2*)(W2bf + (size_t)n * 1024 + k) = p;
}

// K1: part1[b][h] += sum_k dh[b][k]*Wh[h][k], LDS-tiled, Wh read once.
// grid (64 htile, 8 kchunk), 256 thr. part1 pre-zeroed.
__global__ void part1_kernel(const float* __restrict__ dh,
                             const float* __restrict__ Wh,
                             float* __restrict__ part1) {
  __shared__ float whs[16][132];
  __shared__ float dhs[64][132];
  int t = threadIdx.x;
  int h0 = blockIdx.x * 16;
  int k0 = blockIdx.y * 128;
#pragma unroll
  for (int i = 0; i < 2; ++i) {
    int idx = t + 256 * i;          // 512 float4 total
    int r = idx >> 5, c4 = idx & 31;
    float4 x = *(const float4*)(Wh + (size_t)(h0 + r) * 2048 + k0 + c4 * 4);
    *(float4*)&whs[r][c4 * 4] = x;
  }
#pragma unroll
  for (int i = 0; i < 8; ++i) {
    int idx = t + 256 * i;          // 2048 float4 total
    int r = idx >> 5, c4 = idx & 31;
    float4 x = *(const float4*)(dh + (size_t)r * 1024 + k0 + c4 * 4);
    *(float4*)&dhs[r][c4 * 4] = x;
  }
  __syncthreads();
  int b = t >> 2, hg = t & 3;
  float acc[4] = {0.f, 0.f, 0.f, 0.f};
#pragma unroll 4
  for (int k = 0; k < 128; ++k) {
    float d = dhs[b][k];
#pragma unroll
    for (int j = 0; j < 4; ++j) acc[j] += whs[hg * 4 + j][k] * d;
  }
#pragma unroll
  for (int j = 0; j < 4; ++j)
    atomicAdd(&part1[b * 1024 + h0 + hg * 4 + j], acc[j]);
}

// K3: fused GEMM (enc @ W2^T) + tanh + v-dot -> scores.
// 2-phase double-buffered, XOR-swizzled LDS, grid (8 ntile, 256 rowtile).
__global__ __launch_bounds__(256, 2) void gemm_scores(
    const float* __restrict__ enc, const u16* __restrict__ W2bf,
    const float* __restrict__ part1, const float* __restrict__ v,
    float* __restrict__ scores) {
  __shared__ __align__(16) u16 As[2][128 * 64];
  __shared__ __align__(16) u16 Bs[2][128 * 64];
  __shared__ float sc_lds[128];
  const int tid = threadIdx.x;
  const int lane = tid & 63, wid = tid >> 6;
  const int wr = wid >> 1, wc = wid & 1;
  const int l15 = lane & 15, lhi = lane >> 4;
  const int n0 = blockIdx.x * 128;   // 8 n-tiles (fast dim: share A panel)
  const int r0 = blockIdx.y * 128;   // 256 row-tiles
  const int bb = r0 >> 9;

  f32x4 acc[4][4] = {};

  const int brow8 = lane >> 3;                       // 0..7
  const int bks = ((lane & 7) ^ brow8) * 8;          // swizzled k-elem src ofs
  // A staging indices: f = 2*tid + 512*i -> arow = f>>4, c4 = f&15 (even)

  // prologue: stage tile 0 into buf 0
  {
#pragma unroll
    for (int c = 0; c < 4; ++c) {
      const u16* src = W2bf + (size_t)(n0 + c * 32 + wid * 8 + brow8) * 1024 + bks;
      gload_lds16(src, &Bs[0][c * 2048 + wid * 512]);
    }
#pragma unroll
    for (int i = 0; i < 4; ++i) {
      int f = 2 * tid + 512 * i;
      int arow = f >> 4, c4 = f & 15;
      const float4* srcA = (const float4*)(enc + (size_t)(r0 + arow) * 1024 + c4 * 4);
      float4 x = srcA[0], y = srcA[1];
      uint4 p; p.x = pk2(x.x, x.y); p.y = pk2(x.z, x.w);
      p.z = pk2(y.x, y.y); p.w = pk2(y.z, y.w);
      *(uint4*)&As[0][arow * 64 + ((c4 * 4) ^ ((arow & 7) << 3))] = p;
    }
    __syncthreads();
  }

  int p = 0;
  for (int t = 0; t < 16; ++t) {
    float4 xa[4], ya[4];
    if (t < 15) {
      const int kn = (t + 1) * 64;
      // B prefetch: async gload_lds, pre-swizzled per-lane source
#pragma unroll
      for (int c = 0; c < 4; ++c) {
        const u16* src =
            W2bf + (size_t)(n0 + c * 32 + wid * 8 + brow8) * 1024 + kn + bks;
        gload_lds16(src, &Bs[p ^ 1][c * 2048 + wid * 512]);
      }
      // A prefetch: issue f32 loads early (write after MFMA)
#pragma unroll
      for (int i = 0; i < 4; ++i) {
        int f = 2 * tid + 512 * i;
        int arow = f >> 4, c4 = f & 15;
        const float4* srcA =
            (const float4*)(enc + (size_t)(r0 + arow) * 1024 + kn + c4 * 4);
        xa[i] = srcA[0]; ya[i] = srcA[1];
      }
    }
    // compute current buffer
#pragma unroll
    for (int kk = 0; kk < 2; ++kk) {
      bf16x8 af[4], bfr[4];
#pragma unroll
      for (int i = 0; i < 4; ++i) {
        int ar = wr * 64 + i * 16 + l15;
        af[i] = *(const bf16x8*)&As[p][ar * 64 + ((kk * 32 + lhi * 8) ^ ((ar & 7) << 3))];
      }
#pragma unroll
      for (int j = 0; j < 4; ++j) {
        int br = wc * 64 + j * 16 + l15;
        bfr[j] = *(const bf16x8*)&Bs[p][br * 64 + ((kk * 32 + lhi * 8) ^ ((br & 7) << 3))];
      }
#pragma unroll
      for (int i = 0; i < 4; ++i)
#pragma unroll
        for (int j = 0; j < 4; ++j)
          acc[i][j] = __builtin_amdgcn_mfma_f32_16x16x32_bf16(
              af[i], bfr[j], acc[i][j], 0, 0, 0);
    }
    if (t < 15) {
      // cvt + swizzled LDS write of prefetched A
#pragma unroll
      for (int i = 0; i < 4; ++i) {
        int f = 2 * tid + 512 * i;
        int arow = f >> 4, c4 = f & 15;
        uint4 pw;
        pw.x = pk2(xa[i].x, xa[i].y); pw.y = pk2(xa[i].z, xa[i].w);
        pw.z = pk2(ya[i].x, ya[i].y); pw.w = pk2(ya[i].z, ya[i].w);
        *(uint4*)&As[p ^ 1][arow * 64 + ((c4 * 4) ^ ((arow & 7) << 3))] = pw;
      }
      __syncthreads();
      p ^= 1;
    }
  }

  // epilogue: e = tanh(acc + part1[b][col]); score partial += e * v[col]
  if (tid < 128) sc_lds[tid] = 0.f;
  __syncthreads();
  float ps[4][4] = {};
#pragma unroll
  for (int j = 0; j < 4; ++j) {
    int col = n0 + wc * 64 + j * 16 + l15;
    float pv = part1[bb * 1024 + col];
    float vv = v[col];
#pragma unroll
    for (int i = 0; i < 4; ++i)
#pragma unroll
      for (int q = 0; q < 4; ++q)
        ps[i][q] += tanh_fast(acc[i][j][q] + pv) * vv;
  }
#pragma unroll
  for (int i = 0; i < 4; ++i)
#pragma unroll
    for (int q = 0; q < 4; ++q)
      atomicAdd(&sc_lds[wr * 64 + i * 16 + lhi * 4 + q], ps[i][q]);
  __syncthreads();
  if (tid < 128) atomicAdd(&scores[r0 + tid], sc_lds[tid]);
}

// K4: softmax over batch dim (axis=0) per s-column, times mask[s][b]
__global__ void softmax_col(const float* __restrict__ scores,
                            const float* __restrict__ mask,
                            float* __restrict__ a_raw) {
  int s = blockIdx.x;
  int b = threadIdx.x;      // 64 = 1 wave
  float x = scores[b * 512 + s];
  float m = x;
  for (int o = 32; o; o >>= 1) m = fmaxf(m, __shfl_xor(m, o));
  float e = __expf(x - m);
  float sum = e;
  for (int o = 32; o; o >>= 1) sum += __shfl_xor(sum, o);
  a_raw[b * 512 + s] = (e / sum) * mask[s * 64 + b];
}

// K5: normalize each b-row over s
__global__ void norm_rows(const float* __restrict__ a_raw,
                          float* __restrict__ out_a) {
  __shared__ float wsum[4];
  int b = blockIdx.x, t = threadIdx.x;   // 256
  float va = a_raw[b * 512 + t];
  float vb = a_raw[b * 512 + 256 + t];
  float sum = va + vb;
  for (int o = 32; o; o >>= 1) sum += __shfl_xor(sum, o);
  if ((t & 63) == 0) wsum[t >> 6] = sum;
  __syncthreads();
  float tot = wsum[0] + wsum[1] + wsum[2] + wsum[3];
  float inv = 1.f / (tot + 1e-10f);
  out_a[b * 512 + t] = va * inv;
  out_a[b * 512 + 256 + t] = vb * inv;
}

// K6: context[b][h] += sum_{s in chunk} a[b][s]*enc[b][s][h]
// grid (64 b, 4 hc, 8 sc), 256 thr. ctx pre-zeroed.
__global__ void context_kernel(const float* __restrict__ a,
                               const float* __restrict__ enc,
                               float* __restrict__ ctx) {
  int b = blockIdx.x, hc = blockIdx.y, sc = blockIdx.z, t = threadIdx.x;
  int h = hc * 256 + t;
  const float* ep = enc + (size_t)b * 512 * 1024 + (size_t)sc * 64 * 1024 + h;
  const float* ap = a + b * 512 + sc * 64;
  float acc = 0.f;
#pragma unroll 8
  for (int s = 0; s < 64; ++s) acc += ap[s] * ep[(size_t)s * 1024];
  atomicAdd(&ctx[b * 1024 + h], acc);
}

extern "C" void kernel_launch(void* const* d_in, const int* in_sizes, int n_in,
                              void* d_out, int out_size, void* d_ws,
                              size_t ws_size, hipStream_t stream) {
  const float* enc  = (const float*)d_in[0];
  const float* dh   = (const float*)d_in[1];
  const float* mask = (const float*)d_in[2];
  const float* Wh   = (const float*)d_in[3];
  const float* v    = (const float*)d_in[4];
  float* out_a   = (float*)d_out;         // [64,1,512]  = 32768
  float* out_ctx = out_a + M_;            // [64,1,1024] = 65536

  char* ws = (char*)d_ws;
  u16*   W2bf   = (u16*)ws;                                   // 2 MB
  float* part1  = (float*)(ws + (2u << 20));                  // 256 KB
  float* scores = (float*)(ws + (2u << 20) + (256u << 10));   // 128 KB
  float* a_raw  = (float*)(ws + (2u << 20) + (384u << 10));   // 128 KB

  hipMemsetAsync(scores, 0, M_ * sizeof(float), stream);
  hipMemsetAsync(part1, 0, B_ * H_ * sizeof(float), stream);
  hipMemsetAsync(out_ctx, 0, B_ * H_ * sizeof(float), stream);
  conv_w2<<<1024, 256, 0, stream>>>(Wh, W2bf);
  part1_kernel<<<dim3(64, 8), 256, 0, stream>>>(dh, Wh, part1);
  gemm_scores<<<dim3(8, 256), 256, 0, stream>>>(enc, W2bf, part1, v, scores);
  softmax_col<<<512, 64, 0, stream>>>(scores, mask, a_raw);
  norm_rows<<<64, 256, 0, stream>>>(a_raw, out_a);
  context_kernel<<<dim3(64, 4, 8), 256, 0, stream>>>(out_a, enc, out_ctx);
}

// Round 5
// 436.028 us; speedup vs baseline: 1.0455x; 1.0229x over previous
//
#include <hip/hip_runtime.h>

#define B_ 64
#define S_ 512
#define H_ 1024
#define M_ (B_*S_)   // 32768

typedef unsigned int u32;
typedef unsigned short u16;
typedef __attribute__((ext_vector_type(8))) short bf16x8;
typedef __attribute__((ext_vector_type(4))) float f32x4;

__device__ __forceinline__ u16 f2bf(float f) {
  u32 u = __builtin_bit_cast(u32, f);
  u += 0x7fffu + ((u >> 16) & 1u);
  return (u16)(u >> 16);
}
__device__ __forceinline__ u32 pk2(float a, float b) {
  return (u32)f2bf(a) | ((u32)f2bf(b) << 16);
}
__device__ __forceinline__ float tanh_fast(float x) {
  x = fminf(fmaxf(x, -20.f), 20.f);
  float e = __expf(2.f * x);
  return (e - 1.f) / (e + 1.f);
}
__device__ __forceinline__ void gload_lds16(const u16* g, u16* l) {
  __builtin_amdgcn_global_load_lds(
      (const __attribute__((address_space(1))) u32*)g,
      (__attribute__((address_space(3))) u32*)l, 16, 0, 0);
}

// grid decode: 8 n-tiles of a row-panel -> consecutive slots on ONE XCD
__device__ __forceinline__ void decode_bid(int bid, int& r0, int& n0) {
  int nt = (bid >> 3) & 7;
  int rp = ((bid >> 6) << 3) | (bid & 7);
  r0 = rp * 128; n0 = nt * 128;
}

// K-1: enc f32 -> bf16, linear [32768][1024]
__global__ void conv_enc(const float* __restrict__ e, u16* __restrict__ o) {
  int g0 = blockIdx.x * 2048 + threadIdx.x;
#pragma unroll
  for (int j = 0; j < 8; ++j) {
    int g = g0 + j * 256;                      // 8-elem granule
    const float4* s = (const float4*)(e + (size_t)g * 8);
    float4 x = s[0], y = s[1];
    uint4 p;
    p.x = pk2(x.x, x.y); p.y = pk2(x.z, x.w);
    p.z = pk2(y.x, y.y); p.w = pk2(y.z, y.w);
    *(uint4*)(o + (size_t)g * 8) = p;
  }
}

// K0: W2bf[n][k] = bf16(W_h[n][1024+k])
__global__ void conv_w2(const float* __restrict__ Wh, u16* __restrict__ W2bf) {
  int idx = blockIdx.x * 256 + threadIdx.x;
  int n = idx >> 8;
  int k = (idx & 255) * 4;
  float4 x = *(const float4*)(Wh + (size_t)n * 2048 + 1024 + k);
  uint2 p; p.x = pk2(x.x, x.y); p.y = pk2(x.z, x.w);
  *(uint2*)(W2bf + (size_t)n * 1024 + k) = p;
}

// K1: part1[b][h] = sum_k dh[b][k]*Wh[h][k], full-K in block, no atomics
__global__ void part1_kernel(const float* __restrict__ dh,
                             const float* __restrict__ Wh,
                             float* __restrict__ part1) {
  __shared__ float whs[16][132];
  __shared__ float dhs[64][132];
  int t = threadIdx.x;
  int h0 = blockIdx.x * 16;
  int b = t >> 2, hg = t & 3;
  float acc[4] = {0.f, 0.f, 0.f, 0.f};
  for (int kc = 0; kc < 8; ++kc) {
    int k0 = kc * 128;
    __syncthreads();
#pragma unroll
    for (int i = 0; i < 2; ++i) {
      int idx = t + 256 * i; int r = idx >> 5, c4 = idx & 31;
      *(float4*)&whs[r][c4 * 4] =
          *(const float4*)(Wh + (size_t)(h0 + r) * 2048 + k0 + c4 * 4);
    }
#pragma unroll
    for (int i = 0; i < 8; ++i) {
      int idx = t + 256 * i; int r = idx >> 5, c4 = idx & 31;
      *(float4*)&dhs[r][c4 * 4] =
          *(const float4*)(dh + (size_t)r * 1024 + k0 + c4 * 4);
    }
    __syncthreads();
#pragma unroll 4
    for (int k = 0; k < 128; ++k) {
      float d = dhs[b][k];
#pragma unroll
      for (int j = 0; j < 4; ++j) acc[j] += whs[hg * 4 + j][k] * d;
    }
  }
#pragma unroll
  for (int j = 0; j < 4; ++j) part1[b * 1024 + h0 + hg * 4 + j] = acc[j];
}

// K3a: main GEMM — both operands bf16 via gload_lds (pre-swizzled source),
// 2-phase dbuf, one barrier/tile. Writes per-n-tile partial scores.
__global__ __launch_bounds__(256, 2) void gemm_scores_bf(
    const u16* __restrict__ Abf, const u16* __restrict__ W2bf,
    const float* __restrict__ part1, const float* __restrict__ v,
    float* __restrict__ scores_part) {
  __shared__ __align__(16) u16 As[2][128 * 64];
  __shared__ __align__(16) u16 Bs[2][128 * 64];
  __shared__ float sc_lds[128];
  const int tid = threadIdx.x;
  const int lane = tid & 63, wid = tid >> 6;
  const int wr = wid >> 1, wc = wid & 1;
  const int l15 = lane & 15, lhi = lane >> 4;
  int r0, n0; decode_bid(blockIdx.x, r0, n0);
  const int nt = n0 >> 7;
  const int bb = r0 >> 9;
  f32x4 acc[4][4] = {};

  // per-issue pre-swizzled source elem offsets: slot idx=i*256+tid,
  // row=idx>>3, slot granule g=idx&7, source granule g^(row&7)
  int sofs[4];
#pragma unroll
  for (int i = 0; i < 4; ++i) {
    int idx = i * 256 + tid;
    int row = idx >> 3, g = idx & 7;
    sofs[i] = row * 1024 + ((g ^ (row & 7)) << 3);
  }

#define STAGE_T(pbuf, kk0)                                                   \
  do {                                                                       \
    _Pragma("unroll") for (int i_ = 0; i_ < 4; ++i_)                         \
        gload_lds16(Abf + (size_t)r0 * 1024 + (kk0) + sofs[i_],              \
                    &As[pbuf][i_ * 2048 + wid * 512]);                       \
    _Pragma("unroll") for (int i_ = 0; i_ < 4; ++i_)                         \
        gload_lds16(W2bf + (size_t)n0 * 1024 + (kk0) + sofs[i_],             \
                    &Bs[pbuf][i_ * 2048 + wid * 512]);                       \
  } while (0)

  STAGE_T(0, 0);
  __syncthreads();
  int p = 0;
  for (int t = 0; t < 16; ++t) {
    if (t < 15) STAGE_T(p ^ 1, (t + 1) * 64);
#pragma unroll
    for (int kk = 0; kk < 2; ++kk) {
      bf16x8 af[4], bfr[4];
#pragma unroll
      for (int i = 0; i < 4; ++i) {
        int ar = wr * 64 + i * 16 + l15;
        af[i] = *(const bf16x8*)
            &As[p][ar * 64 + (((kk * 4 + lhi) ^ (ar & 7)) << 3)];
      }
#pragma unroll
      for (int j = 0; j < 4; ++j) {
        int br = wc * 64 + j * 16 + l15;
        bfr[j] = *(const bf16x8*)
            &Bs[p][br * 64 + (((kk * 4 + lhi) ^ (br & 7)) << 3)];
      }
#pragma unroll
      for (int i = 0; i < 4; ++i)
#pragma unroll
        for (int j = 0; j < 4; ++j)
          acc[i][j] = __builtin_amdgcn_mfma_f32_16x16x32_bf16(
              af[i], bfr[j], acc[i][j], 0, 0, 0);
    }
    __syncthreads();
    p ^= 1;
  }
#undef STAGE_T

  // epilogue: tanh(acc + part1) dot v -> per-block partial scores
  if (tid < 128) sc_lds[tid] = 0.f;
  __syncthreads();
  float ps[4][4] = {};
#pragma unroll
  for (int j = 0; j < 4; ++j) {
    int col = n0 + wc * 64 + j * 16 + l15;
    float pv = part1[bb * 1024 + col];
    float vv = v[col];
#pragma unroll
    for (int i = 0; i < 4; ++i)
#pragma unroll
      for (int q = 0; q < 4; ++q)
        ps[i][q] += tanh_fast(acc[i][j][q] + pv) * vv;
  }
#pragma unroll
  for (int i = 0; i < 4; ++i)
#pragma unroll
    for (int q = 0; q < 4; ++q)
      atomicAdd(&sc_lds[wr * 64 + i * 16 + lhi * 4 + q], ps[i][q]);
  __syncthreads();
  if (tid < 128) scores_part[nt * M_ + r0 + tid] = sc_lds[tid];
}

// K3b: fallback GEMM (ws too small for enc_bf): inline f32->bf16 A staging
__global__ __launch_bounds__(256, 2) void gemm_scores_inline(
    const float* __restrict__ enc, const u16* __restrict__ W2bf,
    const float* __restrict__ part1, const float* __restrict__ v,
    float* __restrict__ scores_part) {
  __shared__ __align__(16) u16 As[2][128 * 64];
  __shared__ __align__(16) u16 Bs[2][128 * 64];
  __shared__ float sc_lds[128];
  const int tid = threadIdx.x;
  const int lane = tid & 63, wid = tid >> 6;
  const int wr = wid >> 1, wc = wid & 1;
  const int l15 = lane & 15, lhi = lane >> 4;
  int r0, n0; decode_bid(blockIdx.x, r0, n0);
  const int nt = n0 >> 7;
  const int bb = r0 >> 9;
  f32x4 acc[4][4] = {};
  const int brow8 = lane >> 3;
  const int bks = ((lane & 7) ^ brow8) * 8;
  {
#pragma unroll
    for (int c = 0; c < 4; ++c)
      gload_lds16(W2bf + (size_t)(n0 + c * 32 + wid * 8 + brow8) * 1024 + bks,
                  &Bs[0][c * 2048 + wid * 512]);
#pragma unroll
    for (int i = 0; i < 4; ++i) {
      int f = 2 * tid + 512 * i;
      int arow = f >> 4, c4 = f & 15;
      const float4* srcA =
          (const float4*)(enc + (size_t)(r0 + arow) * 1024 + c4 * 4);
      float4 x = srcA[0], y = srcA[1];
      uint4 pw; pw.x = pk2(x.x, x.y); pw.y = pk2(x.z, x.w);
      pw.z = pk2(y.x, y.y); pw.w = pk2(y.z, y.w);
      *(uint4*)&As[0][arow * 64 + ((c4 * 4) ^ ((arow & 7) << 3))] = pw;
    }
    __syncthreads();
  }
  int p = 0;
  for (int t = 0; t < 16; ++t) {
    float4 xa[4], ya[4];
    if (t < 15) {
      const int kn = (t + 1) * 64;
#pragma unroll
      for (int c = 0; c < 4; ++c)
        gload_lds16(
            W2bf + (size_t)(n0 + c * 32 + wid * 8 + brow8) * 1024 + kn + bks,
            &Bs[p ^ 1][c * 2048 + wid * 512]);
#pragma unroll
      for (int i = 0; i < 4; ++i) {
        int f = 2 * tid + 512 * i;
        int arow = f >> 4, c4 = f & 15;
        const float4* srcA =
            (const float4*)(enc + (size_t)(r0 + arow) * 1024 + kn + c4 * 4);
        xa[i] = srcA[0]; ya[i] = srcA[1];
      }
    }
#pragma unroll
    for (int kk = 0; kk < 2; ++kk) {
      bf16x8 af[4], bfr[4];
#pragma unroll
      for (int i = 0; i < 4; ++i) {
        int ar = wr * 64 + i * 16 + l15;
        af[i] = *(const bf16x8*)
            &As[p][ar * 64 + ((kk * 32 + lhi * 8) ^ ((ar & 7) << 3))];
      }
#pragma unroll
      for (int j = 0; j < 4; ++j) {
        int br = wc * 64 + j * 16 + l15;
        bfr[j] = *(const bf16x8*)
            &Bs[p][br * 64 + ((kk * 32 + lhi * 8) ^ ((br & 7) << 3))];
      }
#pragma unroll
      for (int i = 0; i < 4; ++i)
#pragma unroll
        for (int j = 0; j < 4; ++j)
          acc[i][j] = __builtin_amdgcn_mfma_f32_16x16x32_bf16(
              af[i], bfr[j], acc[i][j], 0, 0, 0);
    }
    if (t < 15) {
#pragma unroll
      for (int i = 0; i < 4; ++i) {
        int f = 2 * tid + 512 * i;
        int arow = f >> 4, c4 = f & 15;
        uint4 pw;
        pw.x = pk2(xa[i].x, xa[i].y); pw.y = pk2(xa[i].z, xa[i].w);
        pw.z = pk2(ya[i].x, ya[i].y); pw.w = pk2(ya[i].z, ya[i].w);
        *(uint4*)&As[p ^ 1][arow * 64 + ((c4 * 4) ^ ((arow & 7) << 3))] = pw;
      }
      __syncthreads();
      p ^= 1;
    }
  }
  if (tid < 128) sc_lds[tid] = 0.f;
  __syncthreads();
  float ps[4][4] = {};
#pragma unroll
  for (int j = 0; j < 4; ++j) {
    int col = n0 + wc * 64 + j * 16 + l15;
    float pv = part1[bb * 1024 + col];
    float vv = v[col];
#pragma unroll
    for (int i = 0; i < 4; ++i)
#pragma unroll
      for (int q = 0; q < 4; ++q)
        ps[i][q] += tanh_fast(acc[i][j][q] + pv) * vv;
  }
#pragma unroll
  for (int i = 0; i < 4; ++i)
#pragma unroll
    for (int q = 0; q < 4; ++q)
      atomicAdd(&sc_lds[wr * 64 + i * 16 + lhi * 4 + q], ps[i][q]);
  __syncthreads();
  if (tid < 128) scores_part[nt * M_ + r0 + tid] = sc_lds[tid];
}

// K4: sum 8 partials, softmax over batch dim (axis=0), times mask
__global__ void softmax_col(const float* __restrict__ sp,
                            const float* __restrict__ mask,
                            float* __restrict__ a_raw) {
  int s = blockIdx.x * 4 + (threadIdx.x >> 6);
  int b = threadIdx.x & 63;
  float x = 0.f;
#pragma unroll
  for (int n = 0; n < 8; ++n) x += sp[n * M_ + b * 512 + s];
  float m = x;
  for (int o = 32; o; o >>= 1) m = fmaxf(m, __shfl_xor(m, o));
  float e = __expf(x - m);
  float sum = e;
  for (int o = 32; o; o >>= 1) sum += __shfl_xor(sum, o);
  a_raw[b * 512 + s] = (e / sum) * mask[s * 64 + b];
}

// K5: normalize each b-row over s
__global__ void norm_rows(const float* __restrict__ a_raw,
                          float* __restrict__ out_a) {
  __shared__ float wsum[4];
  int b = blockIdx.x, t = threadIdx.x;   // 256
  float va = a_raw[b * 512 + t];
  float vb = a_raw[b * 512 + 256 + t];
  float sum = va + vb;
  for (int o = 32; o; o >>= 1) sum += __shfl_xor(sum, o);
  if ((t & 63) == 0) wsum[t >> 6] = sum;
  __syncthreads();
  float tot = wsum[0] + wsum[1] + wsum[2] + wsum[3];
  float inv = 1.f / (tot + 1e-10f);
  out_a[b * 512 + t] = va * inv;
  out_a[b * 512 + 256 + t] = vb * inv;
}

// K6: context[b][h] = sum_s a[b][s]*enc[b][s][h]; s split in-block, no atomics
__global__ void context_kernel(const float* __restrict__ a,
                               const float* __restrict__ enc,
                               float* __restrict__ ctx) {
  __shared__ float red[128];
  int b = blockIdx.x, hc = blockIdx.y, t = threadIdx.x;  // 256 thr
  int h = hc * 128 + (t & 127);
  int sh = t >> 7;
  const float* ep = enc + (size_t)b * 524288 + (size_t)sh * 262144 + h;
  const float* ap = a + b * 512 + sh * 256;
  float acc = 0.f;
#pragma unroll 8
  for (int s = 0; s < 256; ++s) acc += ap[s] * ep[(size_t)s * 1024];
  if (sh) red[t & 127] = acc;
  __syncthreads();
  if (!sh) ctx[b * 1024 + h] = acc + red[t];
}

extern "C" void kernel_launch(void* const* d_in, const int* in_sizes, int n_in,
                              void* d_out, int out_size, void* d_ws,
                              size_t ws_size, hipStream_t stream) {
  const float* enc  = (const float*)d_in[0];
  const float* dh   = (const float*)d_in[1];
  const float* mask = (const float*)d_in[2];
  const float* Wh   = (const float*)d_in[3];
  const float* v    = (const float*)d_in[4];
  float* out_a   = (float*)d_out;         // [64,1,512]
  float* out_ctx = out_a + M_;            // [64,1,1024]

  char* ws = (char*)d_ws;
  const size_t SZ_ENC = (size_t)M_ * H_ * 2;        // 67.1 MB
  u16*   W2bf; u16* encbf = nullptr;
  float *part1, *sp, *a_raw;
  bool big = ws_size >= SZ_ENC + (4u << 20);
  if (big) {
    encbf = (u16*)ws;
    W2bf  = (u16*)(ws + SZ_ENC);
    part1 = (float*)(ws + SZ_ENC + (2u << 20));
    sp    = (float*)(ws + SZ_ENC + (2u << 20) + (256u << 10));
    a_raw = (float*)(ws + SZ_ENC + (2u << 20) + (256u << 10) + (1u << 20));
  } else {
    W2bf  = (u16*)ws;
    part1 = (float*)(ws + (2u << 20));
    sp    = (float*)(ws + (2u << 20) + (256u << 10));
    a_raw = (float*)(ws + (2u << 20) + (256u << 10) + (1u << 20));
  }

  conv_w2<<<1024, 256, 0, stream>>>(Wh, W2bf);
  part1_kernel<<<64, 256, 0, stream>>>(dh, Wh, part1);
  if (big) {
    conv_enc<<<2048, 256, 0, stream>>>(enc, encbf);
    gemm_scores_bf<<<2048, 256, 0, stream>>>(encbf, W2bf, part1, v, sp);
  } else {
    gemm_scores_inline<<<2048, 256, 0, stream>>>(enc, W2bf, part1, v, sp);
  }
  softmax_col<<<128, 256, 0, stream>>>(sp, mask, a_raw);
  norm_rows<<<64, 256, 0, stream>>>(a_raw, out_a);
  context_kernel<<<dim3(64, 8), 256, 0, stream>>>(out_a, enc, out_ctx);
}

// Round 6
// 415.141 us; speedup vs baseline: 1.0981x; 1.0503x over previous
//
#include <hip/hip_runtime.h>

#define B_ 64
#define S_ 512
#define H_ 1024
#define M_ (B_*S_)   // 32768

typedef unsigned int u32;
typedef unsigned short u16;
typedef __attribute__((ext_vector_type(8))) short bf16x8;
typedef __attribute__((ext_vector_type(4))) float f32x4;

__device__ __forceinline__ u16 f2bf(float f) {
  u32 u = __builtin_bit_cast(u32, f);
  u += 0x7fffu + ((u >> 16) & 1u);
  return (u16)(u >> 16);
}
__device__ __forceinline__ u32 pk2(float a, float b) {
  return (u32)f2bf(a) | ((u32)f2bf(b) << 16);
}
__device__ __forceinline__ float tanh_fast(float x) {
  x = fminf(fmaxf(x, -20.f), 20.f);
  float e = __expf(2.f * x);
  return (e - 1.f) / (e + 1.f);
}
__device__ __forceinline__ void gload_lds16(const u16* g, u16* l) {
  __builtin_amdgcn_global_load_lds(
      (const __attribute__((address_space(1))) u32*)g,
      (__attribute__((address_space(3))) u32*)l, 16, 0, 0);
}

// grid decode: 8 n-tiles of a row-panel -> consecutive slots on ONE XCD
__device__ __forceinline__ void decode_bid(int bid, int& r0, int& n0) {
  int nt = (bid >> 3) & 7;
  int rp = ((bid >> 6) << 3) | (bid & 7);
  r0 = rp * 128; n0 = nt * 128;
}

// K-1: enc f32 -> bf16, linear [32768][1024]
__global__ void conv_enc(const float* __restrict__ e, u16* __restrict__ o) {
  int g0 = blockIdx.x * 2048 + threadIdx.x;
#pragma unroll
  for (int j = 0; j < 8; ++j) {
    int g = g0 + j * 256;
    const float4* s = (const float4*)(e + (size_t)g * 8);
    float4 x = s[0], y = s[1];
    uint4 p;
    p.x = pk2(x.x, x.y); p.y = pk2(x.z, x.w);
    p.z = pk2(y.x, y.y); p.w = pk2(y.z, y.w);
    *(uint4*)(o + (size_t)g * 8) = p;
  }
}

// K0: W2bf[n][k] = bf16(W_h[n][1024+k])
__global__ void conv_w2(const float* __restrict__ Wh, u16* __restrict__ W2bf) {
  int idx = blockIdx.x * 256 + threadIdx.x;
  int n = idx >> 8;
  int k = (idx & 255) * 4;
  float4 x = *(const float4*)(Wh + (size_t)n * 2048 + 1024 + k);
  uint2 p; p.x = pk2(x.x, x.y); p.y = pk2(x.z, x.w);
  *(uint2*)(W2bf + (size_t)n * 1024 + k) = p;
}

// K1: part1[b][h] = sum_k dh[b][k]*Wh[h][k]; vectorized LDS reads
__global__ void part1_kernel(const float* __restrict__ dh,
                             const float* __restrict__ Wh,
                             float* __restrict__ part1) {
  __shared__ float whs[16][132];
  __shared__ float dhs[64][132];
  int t = threadIdx.x;
  int h0 = blockIdx.x * 16;
  int b = t >> 2, hg = t & 3;
  float acc[4] = {0.f, 0.f, 0.f, 0.f};
  for (int kc = 0; kc < 8; ++kc) {
    int k0 = kc * 128;
    __syncthreads();
#pragma unroll
    for (int i = 0; i < 2; ++i) {
      int idx = t + 256 * i; int r = idx >> 5, c4 = idx & 31;
      *(float4*)&whs[r][c4 * 4] =
          *(const float4*)(Wh + (size_t)(h0 + r) * 2048 + k0 + c4 * 4);
    }
#pragma unroll
    for (int i = 0; i < 8; ++i) {
      int idx = t + 256 * i; int r = idx >> 5, c4 = idx & 31;
      *(float4*)&dhs[r][c4 * 4] =
          *(const float4*)(dh + (size_t)r * 1024 + k0 + c4 * 4);
    }
    __syncthreads();
#pragma unroll 4
    for (int k4 = 0; k4 < 32; ++k4) {
      float4 d = *(const float4*)&dhs[b][k4 * 4];
#pragma unroll
      for (int j = 0; j < 4; ++j) {
        float4 w = *(const float4*)&whs[hg * 4 + j][k4 * 4];
        acc[j] += w.x * d.x + w.y * d.y + w.z * d.z + w.w * d.w;
      }
    }
  }
#pragma unroll
  for (int j = 0; j < 4; ++j) part1[b * 1024 + h0 + hg * 4 + j] = acc[j];
}

// K3a: main GEMM, counted-vmcnt depth-2 pipeline, raw barriers (no drains).
// Writes transposed per-n-tile partial scores spT[nt][s][b].
__global__ __launch_bounds__(256, 2) void gemm_scores_bf(
    const u16* __restrict__ Abf, const u16* __restrict__ W2bf,
    const float* __restrict__ part1, const float* __restrict__ v,
    float* __restrict__ spT) {
  __shared__ __align__(16) u16 As[2][128 * 64];
  __shared__ __align__(16) u16 Bs[2][128 * 64];
  __shared__ float sc_lds[128];
  const int tid = threadIdx.x;
  const int lane = tid & 63, wid = tid >> 6;
  const int wr = wid >> 1, wc = wid & 1;
  const int l15 = lane & 15, lhi = lane >> 4;
  int r0, n0; decode_bid(blockIdx.x, r0, n0);
  const int nt = n0 >> 7;
  const int bb = r0 >> 9;
  f32x4 acc[4][4] = {};

  int sofs[4];
#pragma unroll
  for (int i = 0; i < 4; ++i) {
    int idx = i * 256 + tid;
    int row = idx >> 3, g = idx & 7;
    sofs[i] = row * 1024 + ((g ^ (row & 7)) << 3);
  }

#define STAGE_T(pbuf, kk0)                                                   \
  do {                                                                       \
    _Pragma("unroll") for (int i_ = 0; i_ < 4; ++i_)                         \
        gload_lds16(Abf + (size_t)r0 * 1024 + (kk0) + sofs[i_],              \
                    &As[pbuf][i_ * 2048 + wid * 512]);                       \
    _Pragma("unroll") for (int i_ = 0; i_ < 4; ++i_)                         \
        gload_lds16(W2bf + (size_t)n0 * 1024 + (kk0) + sofs[i_],             \
                    &Bs[pbuf][i_ * 2048 + wid * 512]);                       \
  } while (0)

  STAGE_T(0, 0);
  STAGE_T(1, 64);

  for (int t = 0; t < 16; ++t) {
    const int p = t & 1;
    if (t < 15) asm volatile("s_waitcnt vmcnt(8)" ::: "memory");
    else        asm volatile("s_waitcnt vmcnt(0)" ::: "memory");
    __builtin_amdgcn_s_barrier();
    __builtin_amdgcn_sched_barrier(0);
    __builtin_amdgcn_s_setprio(1);
#pragma unroll
    for (int kk = 0; kk < 2; ++kk) {
      bf16x8 af[4], bfr[4];
#pragma unroll
      for (int i = 0; i < 4; ++i) {
        int ar = wr * 64 + i * 16 + l15;
        af[i] = *(const bf16x8*)
            &As[p][ar * 64 + (((kk * 4 + lhi) ^ (ar & 7)) << 3)];
      }
#pragma unroll
      for (int j = 0; j < 4; ++j) {
        int br = wc * 64 + j * 16 + l15;
        bfr[j] = *(const bf16x8*)
            &Bs[p][br * 64 + (((kk * 4 + lhi) ^ (br & 7)) << 3)];
      }
#pragma unroll
      for (int i = 0; i < 4; ++i)
#pragma unroll
        for (int j = 0; j < 4; ++j)
          acc[i][j] = __builtin_amdgcn_mfma_f32_16x16x32_bf16(
              af[i], bfr[j], acc[i][j], 0, 0, 0);
    }
    __builtin_amdgcn_s_setprio(0);
    __builtin_amdgcn_sched_barrier(0);
    __builtin_amdgcn_s_barrier();
    if (t < 14) STAGE_T(p, (t + 2) * 64);
  }
#undef STAGE_T

  if (tid < 128) sc_lds[tid] = 0.f;
  __syncthreads();
  float ps[4][4] = {};
#pragma unroll
  for (int j = 0; j < 4; ++j) {
    int col = n0 + wc * 64 + j * 16 + l15;
    float pv = part1[bb * 1024 + col];
    float vv = v[col];
#pragma unroll
    for (int i = 0; i < 4; ++i)
#pragma unroll
      for (int q = 0; q < 4; ++q)
        ps[i][q] += tanh_fast(acc[i][j][q] + pv) * vv;
  }
#pragma unroll
  for (int i = 0; i < 4; ++i)
#pragma unroll
    for (int q = 0; q < 4; ++q)
      atomicAdd(&sc_lds[wr * 64 + i * 16 + lhi * 4 + q], ps[i][q]);
  __syncthreads();
  if (tid < 128) {
    int row = r0 + tid;
    spT[nt * M_ + (row & 511) * 64 + (row >> 9)] = sc_lds[tid];
  }
}

// K3b: fallback GEMM (small ws): round-5 structure, transposed score write
__global__ __launch_bounds__(256, 2) void gemm_scores_inline(
    const float* __restrict__ enc, const u16* __restrict__ W2bf,
    const float* __restrict__ part1, const float* __restrict__ v,
    float* __restrict__ spT) {
  __shared__ __align__(16) u16 As[2][128 * 64];
  __shared__ __align__(16) u16 Bs[2][128 * 64];
  __shared__ float sc_lds[128];
  const int tid = threadIdx.x;
  const int lane = tid & 63, wid = tid >> 6;
  const int wr = wid >> 1, wc = wid & 1;
  const int l15 = lane & 15, lhi = lane >> 4;
  int r0, n0; decode_bid(blockIdx.x, r0, n0);
  const int nt = n0 >> 7;
  const int bb = r0 >> 9;
  f32x4 acc[4][4] = {};
  const int brow8 = lane >> 3;
  const int bks = ((lane & 7) ^ brow8) * 8;
  {
#pragma unroll
    for (int c = 0; c < 4; ++c)
      gload_lds16(W2bf + (size_t)(n0 + c * 32 + wid * 8 + brow8) * 1024 + bks,
                  &Bs[0][c * 2048 + wid * 512]);
#pragma unroll
    for (int i = 0; i < 4; ++i) {
      int f = 2 * tid + 512 * i;
      int arow = f >> 4, c4 = f & 15;
      const float4* srcA =
          (const float4*)(enc + (size_t)(r0 + arow) * 1024 + c4 * 4);
      float4 x = srcA[0], y = srcA[1];
      uint4 pw; pw.x = pk2(x.x, x.y); pw.y = pk2(x.z, x.w);
      pw.z = pk2(y.x, y.y); pw.w = pk2(y.z, y.w);
      *(uint4*)&As[0][arow * 64 + ((c4 * 4) ^ ((arow & 7) << 3))] = pw;
    }
    __syncthreads();
  }
  int p = 0;
  for (int t = 0; t < 16; ++t) {
    float4 xa[4], ya[4];
    if (t < 15) {
      const int kn = (t + 1) * 64;
#pragma unroll
      for (int c = 0; c < 4; ++c)
        gload_lds16(
            W2bf + (size_t)(n0 + c * 32 + wid * 8 + brow8) * 1024 + kn + bks,
            &Bs[p ^ 1][c * 2048 + wid * 512]);
#pragma unroll
      for (int i = 0; i < 4; ++i) {
        int f = 2 * tid + 512 * i;
        int arow = f >> 4, c4 = f & 15;
        const float4* srcA =
            (const float4*)(enc + (size_t)(r0 + arow) * 1024 + kn + c4 * 4);
        xa[i] = srcA[0]; ya[i] = srcA[1];
      }
    }
#pragma unroll
    for (int kk = 0; kk < 2; ++kk) {
      bf16x8 af[4], bfr[4];
#pragma unroll
      for (int i = 0; i < 4; ++i) {
        int ar = wr * 64 + i * 16 + l15;
        af[i] = *(const bf16x8*)
            &As[p][ar * 64 + ((kk * 32 + lhi * 8) ^ ((ar & 7) << 3))];
      }
#pragma unroll
      for (int j = 0; j < 4; ++j) {
        int br = wc * 64 + j * 16 + l15;
        bfr[j] = *(const bf16x8*)
            &Bs[p][br * 64 + ((kk * 32 + lhi * 8) ^ ((br & 7) << 3))];
      }
#pragma unroll
      for (int i = 0; i < 4; ++i)
#pragma unroll
        for (int j = 0; j < 4; ++j)
          acc[i][j] = __builtin_amdgcn_mfma_f32_16x16x32_bf16(
              af[i], bfr[j], acc[i][j], 0, 0, 0);
    }
    if (t < 15) {
#pragma unroll
      for (int i = 0; i < 4; ++i) {
        int f = 2 * tid + 512 * i;
        int arow = f >> 4, c4 = f & 15;
        uint4 pw;
        pw.x = pk2(xa[i].x, xa[i].y); pw.y = pk2(xa[i].z, xa[i].w);
        pw.z = pk2(ya[i].x, ya[i].y); pw.w = pk2(ya[i].z, ya[i].w);
        *(uint4*)&As[p ^ 1][arow * 64 + ((c4 * 4) ^ ((arow & 7) << 3))] = pw;
      }
      __syncthreads();
      p ^= 1;
    }
  }
  if (tid < 128) sc_lds[tid] = 0.f;
  __syncthreads();
  float ps[4][4] = {};
#pragma unroll
  for (int j = 0; j < 4; ++j) {
    int col = n0 + wc * 64 + j * 16 + l15;
    float pv = part1[bb * 1024 + col];
    float vv = v[col];
#pragma unroll
    for (int i = 0; i < 4; ++i)
#pragma unroll
      for (int q = 0; q < 4; ++q)
        ps[i][q] += tanh_fast(acc[i][j][q] + pv) * vv;
  }
#pragma unroll
  for (int i = 0; i < 4; ++i)
#pragma unroll
    for (int q = 0; q < 4; ++q)
      atomicAdd(&sc_lds[wr * 64 + i * 16 + lhi * 4 + q], ps[i][q]);
  __syncthreads();
  if (tid < 128) {
    int row = r0 + tid;
    spT[nt * M_ + (row & 511) * 64 + (row >> 9)] = sc_lds[tid];
  }
}

// K4: sum 8 partials (coalesced), softmax over b (wave=s, lane=b), xmask,
// write a_rawT[s][b] + per-b row-sum partials -> rowsum atomics
__global__ void softmax_colT(const float* __restrict__ spT,
                             const float* __restrict__ mask,
                             float* __restrict__ a_rawT,
                             float* __restrict__ rowsum) {
  __shared__ float red[4][64];
  int t = threadIdx.x;
  int sl = t >> 6, b = t & 63;
  int s = blockIdx.x * 4 + sl;
  float x = 0.f;
#pragma unroll
  for (int n = 0; n < 8; ++n) x += spT[n * M_ + s * 64 + b];
  float m = x;
  for (int o = 32; o; o >>= 1) m = fmaxf(m, __shfl_xor(m, o));
  float e = __expf(x - m);
  float sum = e;
  for (int o = 32; o; o >>= 1) sum += __shfl_xor(sum, o);
  float av = (e / sum) * mask[s * 64 + b];
  a_rawT[s * 64 + b] = av;
  red[sl][b] = av;
  __syncthreads();
  if (sl == 0)
    atomicAdd(&rowsum[b], red[0][b] + red[1][b] + red[2][b] + red[3][b]);
}

// K5: out_a[b][s] = a_rawT[s][b] / (rowsum[b]+eps)
__global__ void write_a(const float* __restrict__ a_rawT,
                        const float* __restrict__ rowsum,
                        float* __restrict__ out_a) {
  int b = blockIdx.x, s = threadIdx.x;   // 512 thr
  float inv = 1.f / (rowsum[b] + 1e-10f);
  out_a[b * 512 + s] = a_rawT[s * 64 + b] * inv;
}

// K6: ctx_part[sc][b][h] = sum_{s in chunk} a[b][s]*enc[b][s][h]
__global__ void context_part(const float* __restrict__ a_rawT,
                             const float* __restrict__ rowsum,
                             const float* __restrict__ enc,
                             float* __restrict__ ctx_part) {
  int b = blockIdx.x, sc = blockIdx.y, t = threadIdx.x;  // 256 thr, h4=t
  float inv = 1.f / (rowsum[b] + 1e-10f);
  const float* ep = enc + (size_t)b * 524288 + (size_t)sc * 65536;
  f32x4 acc = {0.f, 0.f, 0.f, 0.f};
#pragma unroll 8
  for (int s = 0; s < 64; ++s) {
    float av = a_rawT[(sc * 64 + s) * 64 + b] * inv;
    float4 e = *(const float4*)(ep + (size_t)s * 1024 + t * 4);
    acc.x += av * e.x; acc.y += av * e.y;
    acc.z += av * e.z; acc.w += av * e.w;
  }
  *(f32x4*)(ctx_part + ((size_t)sc * 64 + b) * 1024 + t * 4) = acc;
}

// K7: out_ctx = sum_sc ctx_part
__global__ void reduce_ctx(const float* __restrict__ ctx_part,
                           float* __restrict__ out_ctx) {
  int idx = blockIdx.x * 256 + threadIdx.x;
  float s = 0.f;
#pragma unroll
  for (int c = 0; c < 8; ++c) s += ctx_part[(size_t)c * 65536 + idx];
  out_ctx[idx] = s;
}

extern "C" void kernel_launch(void* const* d_in, const int* in_sizes, int n_in,
                              void* d_out, int out_size, void* d_ws,
                              size_t ws_size, hipStream_t stream) {
  const float* enc  = (const float*)d_in[0];
  const float* dh   = (const float*)d_in[1];
  const float* mask = (const float*)d_in[2];
  const float* Wh   = (const float*)d_in[3];
  const float* v    = (const float*)d_in[4];
  float* out_a   = (float*)d_out;         // [64,1,512]
  float* out_ctx = out_a + M_;            // [64,1,1024]

  char* ws = (char*)d_ws;
  const size_t SZ_ENC = (size_t)M_ * H_ * 2;        // 67.1 MB
  u16* W2bf; u16* encbf = nullptr;
  char* base;
  bool big = ws_size >= SZ_ENC + (8u << 20);
  if (big) { encbf = (u16*)ws; base = ws + SZ_ENC; }
  else     { base = ws; }
  W2bf            = (u16*)base;                       // 2 MB
  float* part1    = (float*)(base + (2u << 20));      // 256 KB
  float* spT      = (float*)(base + (2u << 20) + (256u << 10));   // 1 MB
  float* a_rawT   = (float*)(base + (3u << 20) + (256u << 10));   // 128 KB
  float* rowsum   = (float*)(base + (3u << 20) + (384u << 10));   // 256 B
  float* ctx_part = (float*)(base + (3u << 20) + (512u << 10));   // 2 MB

  hipMemsetAsync(rowsum, 0, 64 * sizeof(float), stream);
  conv_w2<<<1024, 256, 0, stream>>>(Wh, W2bf);
  part1_kernel<<<64, 256, 0, stream>>>(dh, Wh, part1);
  if (big) {
    conv_enc<<<2048, 256, 0, stream>>>(enc, encbf);
    gemm_scores_bf<<<2048, 256, 0, stream>>>(encbf, W2bf, part1, v, spT);
  } else {
    gemm_scores_inline<<<2048, 256, 0, stream>>>(enc, W2bf, part1, v, spT);
  }
  softmax_colT<<<128, 256, 0, stream>>>(spT, mask, a_rawT, rowsum);
  write_a<<<64, 512, 0, stream>>>(a_rawT, rowsum, out_a);
  context_part<<<dim3(64, 8), 256, 0, stream>>>(a_rawT, rowsum, enc, ctx_part);
  reduce_ctx<<<256, 256, 0, stream>>>(ctx_part, out_ctx);
}